// Round 3
// baseline (18.428 us; speedup 1.0000x reference)
//
#include <hip/hip_runtime.h>

// Reference collapses: softmax over a size-1 axis == 1.0, so m1 == m2 == ones.
//   mask1 = mask2 = 256.0 (N,H,W = 8,14,14 -> 1568 elems each)
//   v1[n,c] = mean_{h,w} l1_org[n,c,h,w]   (8,256 -> 2048 elems), v2 likewise
// Output flat: mask1 [0,1568) | v1 [1568,3616) | mask2 [3616,5184) | v2 [5184,7232)

#define HW        196    // 14*14 == 49 float4
#define NC        2048   // N*C
#define MASKELEMS 1568   // N*H*W

__global__ __launch_bounds__(256) void lra_kernel(const float* __restrict__ l1,
                                                  const float* __restrict__ l2,
                                                  float* __restrict__ out) {
    const int tid  = threadIdx.x;
    const int lane = tid & 63;
    const int wave = tid >> 6;                 // 0..3
    const int nc   = blockIdx.x * 4 + wave;    // 0..2047 : one (n,c) pair, both tensors

    // ---- spatial means: one wave handles row nc of BOTH l1 and l2 ----
    float s1 = 0.0f, s2 = 0.0f;
    if (lane < 49) {                           // 49 float4 = 196 floats, rows 16B-aligned
        float4 a = reinterpret_cast<const float4*>(l1 + (size_t)nc * HW)[lane];
        float4 b = reinterpret_cast<const float4*>(l2 + (size_t)nc * HW)[lane];
        s1 = (a.x + a.y) + (a.z + a.w);
        s2 = (b.x + b.y) + (b.z + b.w);
    }
    #pragma unroll
    for (int off = 32; off > 0; off >>= 1) {
        s1 += __shfl_down(s1, off, 64);
        s2 += __shfl_down(s2, off, 64);
    }
    if (lane == 0) {
        out[MASKELEMS + nc]          = s1 * (1.0f / (float)HW);  // v1
        out[2 * MASKELEMS + NC + nc] = s2 * (1.0f / (float)HW);  // v2
    }

    // ---- constant mask fill, vectorized: 784 float4 stores across first blocks ----
    const int t = blockIdx.x * 256 + tid;      // global thread id
    if (t < 2 * (MASKELEMS / 4)) {             // 784
        const float4 c = make_float4(256.0f, 256.0f, 256.0f, 256.0f);
        float4* dst = (t < MASKELEMS / 4)
                          ? reinterpret_cast<float4*>(out) + t                         // mask1 @ 0
                          : reinterpret_cast<float4*>(out + MASKELEMS + NC) + (t - MASKELEMS / 4); // mask2 @ 3616
        *dst = c;
    }
}

extern "C" void kernel_launch(void* const* d_in, const int* in_sizes, int n_in,
                              void* d_out, int out_size, void* d_ws, size_t ws_size,
                              hipStream_t stream) {
    const float* l1 = (const float*)d_in[0];
    const float* l2 = (const float*)d_in[1];
    // d_in[2] (w) unused: attention masks collapse to ones.
    float* out = (float*)d_out;

    lra_kernel<<<512, 256, 0, stream>>>(l1, l2, out);  // 512 blocks x 4 waves = 2048 (n,c) pairs
}

// Round 4
// 10.080 us; speedup vs baseline: 1.8281x; 1.8281x over previous
//
#include <hip/hip_runtime.h>

// Reference collapses: softmax over a size-1 axis == 1.0, so m1 == m2 == ones.
//   mask1 = mask2 = 256.0 (N,H,W = 8,14,14 -> 1568 elems each)
//   v1[n,c] = mean_{h,w} l1_org[n,c,h,w]   (8,256 -> 2048 elems), v2 likewise
// Output flat: mask1 [0,1568) | v1 [1568,3616) | mask2 [3616,5184) | v2 [5184,7232)
//
// NOTE: this is the round-2 source resubmitted unchanged as an A/B noise probe:
// round-2 measured 11.2 us, round-3 (smaller grid, vectorized fill) measured
// 18.4 us — a delta that exceeds any plausible cost of the change. Re-measuring
// the round-2 binary bounds the harness noise band.

#define HW        196    // 14*14  == 49 float4
#define NC        2048   // N*C
#define MASKELEMS 1568   // N*H*W

__global__ __launch_bounds__(256) void lra_kernel(const float* __restrict__ l1,
                                                  const float* __restrict__ l2,
                                                  float* __restrict__ out) {
    const int tid  = threadIdx.x;
    const int lane = tid & 63;
    const int wave = tid >> 6;                    // 0..3
    const int row  = blockIdx.x * 4 + wave;       // 0..4095 : [0,NC)=l1 rows, [NC,2*NC)=l2 rows

    // ---- spatial mean: one wave per (tensor, n, c) row ----
    const bool first = (row < NC);
    const int  nc    = first ? row : row - NC;
    const float* p   = (first ? l1 : l2) + (size_t)nc * HW;

    float s = 0.0f;
    if (lane < 49) {                              // 49 float4 = 196 floats, base 16B-aligned
        float4 v = reinterpret_cast<const float4*>(p)[lane];
        s = (v.x + v.y) + (v.z + v.w);
    }
    #pragma unroll
    for (int off = 32; off > 0; off >>= 1)
        s += __shfl_down(s, off, 64);

    if (lane == 0) {
        const int base = first ? MASKELEMS : (2 * MASKELEMS + NC);  // 1568 or 5184
        out[base + nc] = s * (1.0f / (float)HW);
    }

    // ---- constant mask fill folded in: first 3136 global threads ----
    const int t = blockIdx.x * 256 + tid;
    if (t < 2 * MASKELEMS) {
        const int off = (t < MASKELEMS) ? t : (t - MASKELEMS) + (MASKELEMS + NC);
        out[off] = 256.0f;
    }
}

extern "C" void kernel_launch(void* const* d_in, const int* in_sizes, int n_in,
                              void* d_out, int out_size, void* d_ws, size_t ws_size,
                              hipStream_t stream) {
    const float* l1 = (const float*)d_in[0];
    const float* l2 = (const float*)d_in[1];
    // d_in[2] (w) unused: attention masks collapse to ones.
    float* out = (float*)d_out;

    lra_kernel<<<1024, 256, 0, stream>>>(l1, l2, out);  // 1024 blocks x 4 waves = 4096 rows
}